// Round 8
// baseline (27.348 us; speedup 1.0000x reference)
//
#include <hip/hip_runtime.h>

// RankPool1d: window=16, stride=1, pad=8 (zeros), rank=8 (0-based 7),
// stable argsort tie-break. Outputs: values f32 [OUT_LEN], sel (as f32) [OUT_LEN].
//
// R8 design: MOUT=4, NO LDS, NO barrier.
//  - o0 = 4*tid, base = 4*tid-8: input float4 loads and value float4 stores
//    both 16B-aligned straight from registers.
//  - sel half starts at OUT_LEN (== 1 mod 4): thread t stores the float4
//    covering outputs 4t+3..4t+6 (byte3 of own packed sel + bytes0..2 of
//    lane+1's, via __shfl_down). Lane 0 patches its first 3 outputs scalar;
//    lane 63 patches its last output scalar. Global output OUT_LEN-1 folded
//    into the last thread (window m=4 lives in w[4..19]).
//  - Working set w[20]+R[20] (~44 array regs) targets the <=64-VGPR bucket
//    -> 8 waves/SIMD (R6/R7 sat at 4 waves: 65-128 bucket).
//
// LAUNCH BOUNDS: bare (256) ONLY. Any min-waves second arg makes hipcc spill
// the w[]/R[] working set to scratch:
//   (256,5) -> VGPR 48, WRITE 79MB, 34.5us;  (256,4) -> VGPR 64, occ 1%, 29.4us
//   (256)   -> no spill. Do not add a second argument.

constexpr int L_IN     = 4194304;
constexpr int OUT_LEN  = L_IN + 1;            // 4194305
constexpr int TPB      = 256;
constexpr int NTHREADS = (OUT_LEN - 1) / 4;   // 1048576
constexpr int NBLK     = NTHREADS / TPB;      // 4096

__global__ __launch_bounds__(TPB) void rankpool_kernel(const float* __restrict__ x,
                                                       float* __restrict__ dout) {
    const int t    = blockIdx.x * TPB + threadIdx.x;   // 0..1048575
    const int lane = threadIdx.x & 63;
    const int o0   = t * 4;
    const int base = o0 - 8;
    const bool isLast = (t == NTHREADS - 1);

    // ---- load 20 inputs (windows m=0..3 need base..base+18; extra needs +19) ----
    float w[20];
    if (base >= 0 && base + 20 <= L_IN) {
        const float4* p = reinterpret_cast<const float4*>(x + base);  // 16B aligned
        #pragma unroll
        for (int q = 0; q < 5; ++q) {
            float4 v = p[q];
            w[4*q+0] = v.x; w[4*q+1] = v.y; w[4*q+2] = v.z; w[4*q+3] = v.w;
        }
    } else {
        #pragma unroll
        for (int i = 0; i < 20; ++i) {
            int g = base + i;
            w[i] = (g >= 0 && g < L_IN) ? x[g] : 0.0f;   // PAD_VALUE = 0
        }
    }

    // ---- biased ranks for window 0 (R[j] = stable rank; init R[j]=j) ----
    int R[20];
    #pragma unroll
    for (int j = 0; j < 16; ++j) R[j] = j;
    #pragma unroll
    for (int j = 0; j < 16; ++j) {
        #pragma unroll
        for (int k = j + 1; k < 16; ++k) {
            int c = (w[k] < w[j]);
            R[j] += c;
            R[k] -= c;
        }
    }

    // ---- 4 windows: select rank==7 (biased target 7+m), then slide ----
    float va[4];
    unsigned pk = 0u;                         // 4 sel bytes
    #pragma unroll
    for (int m = 0; m < 4; ++m) {
        int   sel = 0;
        float val = w[m];
        #pragma unroll
        for (int j = m; j < m + 16; ++j) {
            bool c = (R[j] == 7 + m);
            sel = c ? (j - m) : sel;
            val = c ? w[j]    : val;
        }
        va[m] = val;
        pk |= ((unsigned)sel) << (8 * m);

        if (m < 3) {
            const float wm = w[m];            // departing (oldest)
            const float wn = w[m + 16];       // entering (newest)
            int s = 0;
            #pragma unroll
            for (int j = m + 1; j < m + 16; ++j) {
                R[j] += (int)(w[j] < wm);
                int c2 = (wn < w[j]);
                R[j] += c2;
                s    += c2;
            }
            R[m + 16] = 16 + m - s;           // (15-s) + (m+1) bias
        }
    }

    // ---- value store: one aligned float4 ----
    *reinterpret_cast<float4*>(dout + o0) = make_float4(va[0], va[1], va[2], va[3]);

    // ---- sel store: shfl-shifted aligned float4 ----
    unsigned pn = __shfl_down(pk, 1, 64);     // lane+1's pk (garbage on lane 63)
    float* s0 = dout + OUT_LEN;
    if (lane < 63) {
        // covers outputs o0+3 .. o0+6; addr (OUT_LEN + o0 + 3) % 4 == 0, 16B aligned
        float4 sv = make_float4((float)(pk >> 24),
                                (float)( pn        & 0xffu),
                                (float)((pn >>  8) & 0xffu),
                                (float)((pn >> 16) & 0xffu));
        *reinterpret_cast<float4*>(s0 + o0 + 3) = sv;
    } else {
        s0[o0 + 3] = (float)(pk >> 24);       // own last output only
    }
    if (lane == 0) {                          // own first 3 outputs (prev lane is
        s0[o0 + 0] = (float)( pk        & 0xffu);   // another wave or none)
        s0[o0 + 1] = (float)((pk >>  8) & 0xffu);
        s0[o0 + 2] = (float)((pk >> 16) & 0xffu);
    }

    // ---- final output OUT_LEN-1 (window m=4 of last thread: w[4..19]) ----
    if (isLast) {
        const float wm = w[3], wn = w[19];
        int s = 0;
        #pragma unroll
        for (int j = 4; j < 19; ++j) {
            R[j] += (int)(w[j] < wm);
            int c2 = (wn < w[j]);
            R[j] += c2;
            s    += c2;
        }
        R[19] = 19 - s;                       // (15-s) + 4 bias
        int sel = 0; float val = w[4];
        #pragma unroll
        for (int j = 4; j < 20; ++j) {
            bool c = (R[j] == 11);            // 7 + 4
            sel = c ? (j - 4) : sel;
            val = c ? w[j]    : val;
        }
        dout[OUT_LEN - 1]     = val;
        dout[2 * OUT_LEN - 1] = (float)sel;
    }
}

extern "C" void kernel_launch(void* const* d_in, const int* in_sizes, int n_in,
                              void* d_out, int out_size, void* d_ws, size_t ws_size,
                              hipStream_t stream) {
    const float* x = (const float*)d_in[0];
    float* out = (float*)d_out;
    rankpool_kernel<<<NBLK, TPB, 0, stream>>>(x, out);
}